// Round 9
// baseline (172.119 us; speedup 1.0000x reference)
//
#include <hip/hip_runtime.h>
#include <stdint.h>

// Problem constants: B=16, C=48, H=W=64, N_CORR=2048
#define BB 16
#define HW 4096
#define NC 2048
#define KHW 72           // halfwords per column: 48 data + 24 pad (KB=144 kept for 16B-aligned b128)
#define KB 144           // bytes per column

typedef __attribute__((ext_vector_type(8))) __bf16 bf16x8;
typedef __attribute__((ext_vector_type(8))) short short8;
typedef __attribute__((ext_vector_type(4))) float floatx4;
typedef __attribute__((ext_vector_type(16))) float floatx16;

static __device__ __forceinline__ unsigned short f2bf(float f) {
    unsigned u = __builtin_bit_cast(unsigned, f);
    unsigned r = u + 0x7fffu + ((u >> 16) & 1u);    // RNE
    return (unsigned short)(r >> 16);
}

#define GLD16(g, l) __builtin_amdgcn_global_load_lds((const __attribute__((address_space(1))) void*)(g), (__attribute__((address_space(3))) void*)(l), 16, 0, 0)
#define GLD4(g, l)  __builtin_amdgcn_global_load_lds((const __attribute__((address_space(1))) void*)(g), (__attribute__((address_space(3))) void*)(l), 4, 0, 0)

// ---------------------------------------------------------------------------
// prep_fused (unchanged from R8):
//   blocks [0,512):   normalize 256 cols -> bf16 dbp (KB=144, pad zeros)
//   blocks [512,544): counting sort of each (dir,b) query segment by qi
//   blocks [544,552): zero maxs2enc
// ---------------------------------------------------------------------------
__global__ void prep_fused(const float* __restrict__ x1, const float* __restrict__ x2,
                           const int* __restrict__ ids, const int* __restrict__ fp2,
                           unsigned short* __restrict__ dbp,
                           int* __restrict__ perm, int* __restrict__ qcol_s,
                           int* __restrict__ aqpack, unsigned int* __restrict__ maxs2enc) {
    __shared__ __align__(16) unsigned char slab[36864 + 4096 + 1024];
    int bid = blockIdx.x, tid = threadIdx.x;
    if (bid < 512) {
        int img = bid >> 8;
        int b = (bid >> 4) & 15;
        int p0 = (bid & 15) * 256;
        int w = tid >> 6, l = tid & 63;
        const float* x = img ? x2 : x1;
        const float* base = x + ((size_t)b * 48 + w * 12) * HW + p0 + 4 * l;
        floatx4 v[12];
        floatx4 ps = {0.f, 0.f, 0.f, 0.f};
#pragma unroll
        for (int cc = 0; cc < 12; ++cc) {
            v[cc] = *(const floatx4*)(base + cc * HW);
#pragma unroll
            for (int q = 0; q < 4; ++q) ps[q] = fmaf(v[cc][q], v[cc][q], ps[q]);
        }
        float* psum = (float*)(slab + 36864);             // [4 waves][256 cols]
        float* rbuf = (float*)(slab + 36864 + 4096);      // [256 cols]
        *(floatx4*)(psum + w * 256 + 4 * l) = ps;
        __syncthreads();
        float s = psum[tid] + psum[256 + tid] + psum[512 + tid] + psum[768 + tid];
        rbuf[tid] = 1.f / fmaxf(sqrtf(s), 1e-12f);
        __syncthreads();
        floatx4 rv = *(const floatx4*)(rbuf + 4 * l);
#pragma unroll
        for (int q = 0; q < 4; ++q) {
            unsigned u[6];
#pragma unroll
            for (int p = 0; p < 6; ++p) {
                u[p] = (unsigned)f2bf(v[2 * p][q] * rv[q]) |
                       ((unsigned)f2bf(v[2 * p + 1][q] * rv[q]) << 16);
            }
            unsigned char* dst = slab + (4 * l + q) * KB + w * 24;  // 8-aligned
            *(uint2*)(dst + 0)  = make_uint2(u[0], u[1]);
            *(uint2*)(dst + 8)  = make_uint2(u[2], u[3]);
            *(uint2*)(dst + 16) = make_uint2(u[4], u[5]);
        }
        uint4 z4 = {0u, 0u, 0u, 0u};
#pragma unroll
        for (int z = 0; z < 3; ++z)
            *(uint4*)(slab + tid * KB + 96 + z * 16) = z4;
        __syncthreads();
        unsigned char* dstb = (unsigned char*)dbp + ((size_t)(img * BB + b) * HW + p0) * KB;
#pragma unroll
        for (int rr = 0; rr < 9; ++rr) {                  // 256*144 B, coalesced
            int idx = rr * 4096 + tid * 16;
            *(floatx4*)(dstb + idx) = *(const floatx4*)(slab + idx);
        }
    } else if (bid < 544) {
        int* hist = (int*)slab;
        int* base = hist + 64;
        int seg = bid - 512;                      // dir*16 + b
        int dir = seg >> 4, b = seg & 15;
        if (tid < 64) hist[tid] = 0;
        __syncthreads();
#pragma unroll
        for (int k = 0; k < 8; ++k) {
            int n = k * 256 + tid;
            int idv = ids[b * NC + n];
            int i2 = fp2[b * 2 * NC + n];
            int qi = (dir == 0) ? i2 : (idv >> 6);
            atomicAdd(&hist[qi], 1);
        }
        __syncthreads();
        if (tid == 0) {
            int run = 0;
            for (int k = 0; k < 64; ++k) { base[k] = run; run += hist[k]; }
        }
        __syncthreads();
#pragma unroll
        for (int k = 0; k < 8; ++k) {
            int n = k * 256 + tid;
            int idv = ids[b * NC + n];
            int i2 = fp2[b * 2 * NC + n];
            int j2 = fp2[b * 2 * NC + NC + n];
            int qi, qj, qcol;
            if (dir == 0) { qi = i2; qj = j2; qcol = idv; }
            else          { qi = idv >> 6; qj = idv & 63; qcol = i2 * 64 + j2; }
            int slot = atomicAdd(&base[qi], 1);
            perm[seg * NC + slot] = n;
            qcol_s[seg * NC + slot] = qcol;
            aqpack[seg * NC + slot] = (qi << 8) | qj;
        }
    } else {
        int t = (bid - 544) * 256 + tid;          // [0, 2048)
        uint4* p = (uint4*)maxs2enc;
        uint4 z = {0u, 0u, 0u, 0u};
#pragma unroll
        for (int k = 0; k < 8; ++k) p[k * 2048 + t] = z;
    }
}

// ---------------------------------------------------------------------------
// maxscore_mfma: champion staging (R2-proposal: grid 1024 = 32 seg x 8 mtile
// x 4 nq; 256 q/block, 1024 cols/block, 8 double-buffered 128-col tiles,
// KB=144 b128 LDS reads) with 32x32x16 bf16 MFMA, K=48 NATIVE (3 chained
// MFMA, no zero-pad -> 37% fewer matrix-cycles, 25% fewer ds_reads than the
// 16x16 K=64 version). Wave owns 64 queries (2 mc of 32). C/D mapping:
// col=lane&31, row=(reg&3)+8*(reg>>2)+4*(lane>>5) [verified R7 / m74/m101].
// Plain launch_bounds (R4 lesson: forcing min-waves causes spills).
// ---------------------------------------------------------------------------
static __device__ __forceinline__ void dma_tile(const unsigned char* g, unsigned char* l,
                                                int wave, int lane) {
#pragma unroll
    for (int rr = 0; rr < 4; ++rr)
        GLD16(g + rr * 4096 + wave * 1024 + lane * 16, l + rr * 4096 + wave * 1024);
#pragma unroll
    for (int rr = 0; rr < 2; ++rr)
        GLD4(g + 16384 + rr * 1024 + wave * 256 + lane * 4, l + 16384 + rr * 1024 + wave * 256);
}

__global__ __launch_bounds__(256) void maxscore_mfma(
    const unsigned short* __restrict__ dbp,
    const int* __restrict__ perm, const int* __restrict__ qcol_s,
    const int* __restrict__ aqpack, unsigned int* __restrict__ maxs2enc) {
    __shared__ __align__(16) unsigned char smem[36864];   // 2 db buffers of 18432

    int tid = threadIdx.x, wave = tid >> 6, lane = tid & 63;
    int ml = lane & 31, hl = lane >> 5;
    int gid = blockIdx.x;
    int seg = gid & 31, dir = seg >> 4, b = seg & 15;
    int rest = gid >> 5, mtile = rest & 7, nq = rest >> 3;   // nq in [0,4)
    int qbase = mtile * 256;
    int dbimg = 1 - dir;

    // A-fragments: A[m=ml][k=hl*8+j]; k-step ks -> byte hl*16 + ks*32.
    // 16B gathers straight from dbp (query image = dir; L2-hot).
    const unsigned char* dbQ = (const unsigned char*)(dbp + (size_t)(dir * BB + b) * HW * KHW);
    short8 afr[2][3];
#pragma unroll
    for (int mc = 0; mc < 2; ++mc) {
        int qc = qcol_s[seg * NC + qbase + wave * 64 + mc * 32 + ml];
        const unsigned char* src = dbQ + (size_t)qc * KB + hl * 16;
        afr[mc][0] = *(const short8*)(src);
        afr[mc][1] = *(const short8*)(src + 32);
        afr[mc][2] = *(const short8*)(src + 64);
    }
    // Anchors packed 2 per int: regs rr,rr+1 (row(rr+1)=row(rr)+1 for even rr)
    int qp[2][8];
#pragma unroll
    for (int mc = 0; mc < 2; ++mc)
#pragma unroll
        for (int rp = 0; rp < 8; ++rp) {
            int rr = 2 * rp;
            int row = (rr & 3) + 8 * (rr >> 2) + 4 * hl;
            int slot = seg * NC + qbase + wave * 64 + mc * 32 + row;
            qp[mc][rp] = aqpack[slot] | (aqpack[slot + 1] << 16);
        }
    int wb = seg * NC + qbase + wave * 64;
    int qimin = __builtin_amdgcn_readfirstlane(aqpack[wb] >> 8);
    int qimax = __builtin_amdgcn_readfirstlane(aqpack[wb + 63] >> 8);

    const unsigned char* dsrc =
        (const unsigned char*)(dbp + ((size_t)(dbimg * BB + b) * HW + nq * 1024) * KHW);
    dma_tile(dsrc, smem, wave, lane);                     // prefetch tile 0

    float mx[2][16];
#pragma unroll
    for (int mc = 0; mc < 2; ++mc)
#pragma unroll
        for (int rr = 0; rr < 16; ++rr) mx[mc][rr] = -1e30f;
    float mlf = (float)ml;

    for (int tile = 0; tile < 8; ++tile) {
        unsigned char* buf = smem + (tile & 1) * 18432;
        __syncthreads();
        if (tile + 1 < 8)
            dma_tile(dsrc + (tile + 1) * 18432, smem + ((tile + 1) & 1) * 18432, wave, lane);
        int mi0 = (nq * 1024 + tile * 128) >> 6;          // two db rows per tile
#pragma unroll
        for (int nc = 0; nc < 4; ++nc) {                  // 32-col groups
            int mi = mi0 + (nc >> 1);
            bool active = (mi >= qimin - 4) && (mi <= qimax + 4);   // wave-uniform
            // B-fragments: B[n=ml][k=hl*8+j] for col nc*32+ml
            const unsigned char* cb = buf + (nc * 32 + ml) * KB + hl * 16;
            short8 b0 = *(const short8*)(cb);
            short8 b1 = *(const short8*)(cb + 32);
            short8 b2 = *(const short8*)(cb + 64);
            float jml = (float)(nc * 32) + mlf;           // this lane's col j
            float mi_f = (float)mi;
#pragma unroll
            for (int mc = 0; mc < 2; ++mc) {
                floatx16 acc = {};
                acc = __builtin_amdgcn_mfma_f32_32x32x16_bf16(
                          __builtin_bit_cast(bf16x8, afr[mc][0]),
                          __builtin_bit_cast(bf16x8, b0), acc, 0, 0, 0);
                acc = __builtin_amdgcn_mfma_f32_32x32x16_bf16(
                          __builtin_bit_cast(bf16x8, afr[mc][1]),
                          __builtin_bit_cast(bf16x8, b1), acc, 0, 0, 0);
                acc = __builtin_amdgcn_mfma_f32_32x32x16_bf16(
                          __builtin_bit_cast(bf16x8, afr[mc][2]),
                          __builtin_bit_cast(bf16x8, b2), acc, 0, 0, 0);
                if (!active) {                            // fast: 1 op/elem
#pragma unroll
                    for (int rr = 0; rr < 16; ++rr)
                        mx[mc][rr] = fmaxf(mx[mc][rr], acc[rr]);
                } else {                                  // rare: inline mask
#pragma unroll
                    for (int rp = 0; rp < 8; ++rp) {
                        int ap2 = qp[mc][rp];
#pragma unroll
                        for (int h = 0; h < 2; ++h) {
                            int rr = 2 * rp + h;
                            int ap = (ap2 >> (16 * h)) & 0xffff;
                            bool rowblk = fabsf((float)(ap >> 8) - mi_f) <= 4.0f;
                            bool colblk = fabsf((float)(ap & 255) - jml) <= 4.0f;
                            bool ok = !(rowblk && colblk);
                            mx[mc][rr] = ok ? fmaxf(mx[mc][rr], acc[rr]) : mx[mc][rr];
                        }
                    }
                }
            }
        }
    }

    // reduce max over the 32 cols (lanes sharing hl)
#pragma unroll
    for (int mc = 0; mc < 2; ++mc)
#pragma unroll
        for (int rr = 0; rr < 16; ++rr) {
            float v = mx[mc][rr];
            v = fmaxf(v, __shfl_xor(v, 1, 32));
            v = fmaxf(v, __shfl_xor(v, 2, 32));
            v = fmaxf(v, __shfl_xor(v, 4, 32));
            v = fmaxf(v, __shfl_xor(v, 8, 32));
            v = fmaxf(v, __shfl_xor(v, 16, 32));
            mx[mc][rr] = v;
        }
    if (ml == 0) {                                        // lanes 0 and 32
#pragma unroll
        for (int mc = 0; mc < 2; ++mc)
#pragma unroll
            for (int rr = 0; rr < 16; ++rr) {
                int row = (rr & 3) + 8 * (rr >> 2) + 4 * hl;
                int slot = qbase + wave * 64 + mc * 32 + row;
                int orig = perm[seg * NC + slot];
                float v = mx[mc][rr] + 2.0f;              // > 0: uint-monotone
                atomicMax(&maxs2enc[(size_t)seg * NC + orig],
                          __builtin_bit_cast(unsigned, v));
            }
    }
}

// ---------------------------------------------------------------------------
// loss: pos-distance from dbp bf16 columns (consistent rounding with the neg
// path), decode/merge direction maxes, weighted partial sums. grid = 128.
// ---------------------------------------------------------------------------
__global__ void loss_kernel(const float* __restrict__ att1, const float* __restrict__ att2,
                            const int* __restrict__ ids, const int* __restrict__ fp2,
                            const unsigned short* __restrict__ dbp,
                            const unsigned int* __restrict__ maxs2enc,
                            float* __restrict__ pnum, float* __restrict__ pden) {
    int b = blockIdx.x >> 3, chunk = blockIdx.x & 7;
    int tid = threadIdx.x;
    int n = chunk * 256 + tid;
    int idv = ids[b * NC + n];
    int i2 = fp2[b * 2 * NC + n], j2 = fp2[b * 2 * NC + NC + n];
    const uint4* a4 = (const uint4*)(dbp + ((size_t)(0 * BB + b) * HW + idv) * KHW);
    const uint4* b4 = (const uint4*)(dbp + ((size_t)(1 * BB + b) * HW + i2 * 64 + j2) * KHW);
    float dot = 0.f;
#pragma unroll
    for (int i = 0; i < 6; ++i) {                         // 6 x 16 B = 48 bf16
        uint4 xa = a4[i], xb = b4[i];
        const unsigned* xu = (const unsigned*)&xa;
        const unsigned* yu = (const unsigned*)&xb;
#pragma unroll
        for (int w = 0; w < 4; ++w) {
            float xl = __builtin_bit_cast(float, xu[w] << 16);
            float xh = __builtin_bit_cast(float, xu[w] & 0xffff0000u);
            float yl = __builtin_bit_cast(float, yu[w] << 16);
            float yh = __builtin_bit_cast(float, yu[w] & 0xffff0000u);
            dot = fmaf(xl, yl, fmaf(xh, yh, dot));
        }
    }
    float m0 = __builtin_bit_cast(float, maxs2enc[(size_t)(0 * BB + b) * NC + n]) - 2.0f;
    float m1 = __builtin_bit_cast(float, maxs2enc[(size_t)(1 * BB + b) * NC + n]) - 2.0f;
    float ms = fmaxf(m0, m1);
    float diff = (2.f - 2.f * dot) - (2.f - 2.f * ms);
    float w = att1[b * HW + idv] * att2[b * HW + i2 * 64 + j2];
    float num = w * fmaxf(0.f, 1.f + diff);
    float den = w;
    __shared__ float sn[256], sd[256];
    sn[tid] = num; sd[tid] = den;
    __syncthreads();
    for (int s = 128; s > 0; s >>= 1) {
        if (tid < s) { sn[tid] += sn[tid + s]; sd[tid] += sd[tid + s]; }
        __syncthreads();
    }
    if (tid == 0) { pnum[blockIdx.x] = sn[0]; pden[blockIdx.x] = sd[0]; }
}

__global__ void final_kernel(const float* __restrict__ pnum, const float* __restrict__ pden,
                             float* __restrict__ out) {
    int tid = threadIdx.x;
    __shared__ float r[16];
    if (tid < 16) {
        float n = 0.f, d = 0.f;
#pragma unroll
        for (int c = 0; c < 8; ++c) { n += pnum[tid * 8 + c]; d += pden[tid * 8 + c]; }
        r[tid] = n / d;
    }
    __syncthreads();
    if (tid == 0) {
        float s = 0.f;
#pragma unroll
        for (int k = 0; k < 16; ++k) s += r[k];
        out[0] = s * (1.f / BB);
    }
}

extern "C" void kernel_launch(void* const* d_in, const int* in_sizes, int n_in,
                              void* d_out, int out_size, void* d_ws, size_t ws_size,
                              hipStream_t stream) {
    const float* x1  = (const float*)d_in[0];
    const float* x2  = (const float*)d_in[1];
    const float* att1 = (const float*)d_in[2];
    const float* att2 = (const float*)d_in[3];
    const int* ids   = (const int*)d_in[4];
    const int* fp2   = (const int*)d_in[5];
    float* out = (float*)d_out;

    // ws layout (bytes), ~19.9 MB. NOTE (R8): the harness re-poisons the FULL
    // 256 MiB d_ws allocation every iteration (~43 us at HBM BW) regardless of
    // how much we use — ws sizing is perf-neutral; layout chosen for clarity.
    unsigned char* w = (unsigned char*)d_ws;
    unsigned short* dbp = (unsigned short*)(w + 0);          // 2*16*4096*144 = 18,874,368
    int* perm    = (int*)(w + 18874368);                     // 32*2048*4 = 262,144
    int* qcol_s  = (int*)(w + 19136512);                     // 262,144
    int* aqpack  = (int*)(w + 19398656);                     // 262,144
    unsigned int* maxs2enc = (unsigned int*)(w + 19660800);  // 262,144
    float* pnum  = (float*)(w + 19922944);                   // 512
    float* pden  = (float*)(w + 19923456);                   // 512

    prep_fused<<<dim3(552), dim3(256), 0, stream>>>(x1, x2, ids, fp2, dbp,
                                                    perm, qcol_s, aqpack, maxs2enc);
    maxscore_mfma<<<dim3(1024), dim3(256), 0, stream>>>(dbp, perm, qcol_s, aqpack, maxs2enc);
    loss_kernel<<<dim3(128), dim3(256), 0, stream>>>(att1, att2, ids, fp2, dbp, maxs2enc, pnum, pden);
    final_kernel<<<dim3(1), dim3(64), 0, stream>>>(pnum, pden, out);
}